// Round 2
// baseline (242.432 us; speedup 1.0000x reference)
//
#include <hip/hip_runtime.h>

// BilinearSamplerLayer: image [16,256,256,32] f32, flow [16,256,256,2] f32
// -> out [16,256,256,32] f32.
// 8 lanes per pixel, one float4 channel-quad per lane.
// B=16, H=W=256, C=32 are compile-time constants (powers of two).

__global__ __launch_bounds__(256) void bilinear_sampler_kernel(
    const float* __restrict__ image,
    const float* __restrict__ flow,
    float* __restrict__ out)
{
    constexpr int H = 256, W = 256, C = 32;

    const int gid = blockIdx.x * 256 + threadIdx.x;   // 8,388,608 threads total
    const int pid = gid >> 3;                         // pixel id in [0, 1M)
    const int cq  = (gid & 7) << 2;                   // channel offset 0,4,...,28

    // pid = ((b*H + yi)*W + xi)
    const int b   = pid >> 16;                        // / (H*W)
    const int rem = pid & 65535;
    const int yi  = rem >> 8;                         // / W
    const int xi  = rem & 255;

    // flow for this pixel (lanes of the same pixel read the same 8B — coalesced)
    const float2 f = *reinterpret_cast<const float2*>(flow + (size_t)pid * 2);

    // base grid: linspace(-1,1,N) -> -1 + 2*i/(N-1)
    const float x_base = fmaf((float)xi, 2.0f / 255.0f, -1.0f);
    const float y_base = fmaf((float)yi, 2.0f / 255.0f, -1.0f);

    float x = fmaf(0.3f, f.x, x_base);
    float y = fmaf(0.3f, f.y, y_base);
    // map to pixel coords with W/2, H/2 (per reference, NOT (W-1)/2)
    x = (x + 1.0f) * (0.5f * (float)W);
    y = (y + 1.0f) * (0.5f * (float)H);

    const float fx0 = floorf(x);
    const float fy0 = floorf(y);
    int x0 = (int)fx0;
    int y0 = (int)fy0;
    int x1 = x0 + 1;
    int y1 = y0 + 1;
    x0 = min(max(x0, 0), W - 1);
    x1 = min(max(x1, 0), W - 1);
    y0 = min(max(y0, 0), H - 1);
    y1 = min(max(y1, 0), H - 1);

    const float x0f = (float)x0, x1f = (float)x1;
    const float y0f = (float)y0, y1f = (float)y1;
    const float wa = (x1f - x) * (y1f - y);
    const float wb = (x1f - x) * (y - y0f);
    const float wc = (x - x0f) * (y1f - y);
    const float wd = (x - x0f) * (y - y0f);

    const int base = b << 16;                          // b * H * W
    const size_t row0 = (size_t)(base + y0 * W) * C;
    const size_t row1 = (size_t)(base + y1 * W) * C;

    const float4 Ia = *reinterpret_cast<const float4*>(image + row0 + (size_t)x0 * C + cq);
    const float4 Ib = *reinterpret_cast<const float4*>(image + row1 + (size_t)x0 * C + cq);
    const float4 Ic = *reinterpret_cast<const float4*>(image + row0 + (size_t)x1 * C + cq);
    const float4 Id = *reinterpret_cast<const float4*>(image + row1 + (size_t)x1 * C + cq);

    float4 o;
    o.x = wa * Ia.x + wb * Ib.x + wc * Ic.x + wd * Id.x;
    o.y = wa * Ia.y + wb * Ib.y + wc * Ic.y + wd * Id.y;
    o.z = wa * Ia.z + wb * Ib.z + wc * Ic.z + wd * Id.z;
    o.w = wa * Ia.w + wb * Ib.w + wc * Ic.w + wd * Id.w;

    *reinterpret_cast<float4*>(out + (size_t)pid * C + cq) = o;
}

extern "C" void kernel_launch(void* const* d_in, const int* in_sizes, int n_in,
                              void* d_out, int out_size, void* d_ws, size_t ws_size,
                              hipStream_t stream) {
    const float* image = (const float*)d_in[0];
    const float* flow  = (const float*)d_in[1];
    float* out = (float*)d_out;

    // total threads = B*H*W*C/4 = 16*256*256*8 = 8,388,608 ; block = 256
    const int blocks = 8388608 / 256; // 32768
    bilinear_sampler_kernel<<<blocks, 256, 0, stream>>>(image, flow, out);
}